// Round 9
// baseline (17807.280 us; speedup 1.0000x reference)
//
#include <hip/hip_runtime.h>

typedef __attribute__((ext_vector_type(8))) short short8;
typedef __attribute__((ext_vector_type(4))) short short4v;
typedef __attribute__((ext_vector_type(4))) float f32x4;
typedef unsigned long long u64;

__device__ __forceinline__ short f2bf(float x) {
  union { float f; unsigned u; } v; v.f = x;
  unsigned r = v.u + 0x7fffu + ((v.u >> 16) & 1u);   // RNE
  return (short)(r >> 16);
}
__device__ __forceinline__ float bf2f(short b) {
  union { unsigned u; float f; } v; v.u = ((unsigned)(unsigned short)b) << 16;
  return v.f;
}

#define GLOAD_LDS16(g, l) __builtin_amdgcn_global_load_lds( \
    (const __attribute__((address_space(1))) void*)(g),     \
    (__attribute__((address_space(3))) void*)(l), 16, 0, 0)

// ---------------- f32 -> bf16 conversion ----------------
__global__ void k_cvt(const float* __restrict__ s, short* __restrict__ d, int n) {
  int stride = gridDim.x * blockDim.x * 4;
  for (int i = (blockIdx.x * blockDim.x + threadIdx.x) * 4; i < n; i += stride) {
    float4 v = *(const float4*)(s + i);
    short4v o;
    o.x = f2bf(v.x); o.y = f2bf(v.y); o.z = f2bf(v.z); o.w = f2bf(v.w);
    *(short4v*)(d + i) = o;
  }
}

// ---------------- combined bias (fwd 0:4096, rev 4096:8192) ----------------
__global__ void k_bias(const float* __restrict__ bif, const float* __restrict__ bhf,
                       const float* __restrict__ bir, const float* __restrict__ bhr,
                       float* __restrict__ o) {
  int i = blockIdx.x * 256 + threadIdx.x;
  o[i] = (i < 4096) ? (bif[i] + bhf[i]) : (bir[i - 4096] + bhr[i - 4096]);
}

// ---------------- zero the tagged h buffer (49152 u64) ----------------
__global__ void k_zero_h(u64* __restrict__ p) { p[blockIdx.x * 256 + threadIdx.x] = 0; }

// ---------------- input GEMM: C[M][N] = A[M][K] * Bt[N][K]^T + bias, bf16 out ----
__global__ void __launch_bounds__(256) k_gemm(
    const short* __restrict__ A, const short* __restrict__ Bt,
    const float* __restrict__ bias, short* __restrict__ C,
    int M, int N, int K)
{
  __shared__ short Al[128 * 64];
  __shared__ short Bl[128 * 64];
  const int nm = M >> 7;
  int wg = blockIdx.x;
  int q = gridDim.x >> 3;                   // gridDim.x % 8 == 0 (8192)
  wg = (wg & 7) * q + (wg >> 3);            // XCD-aware swizzle (bijective)
  const int mt = wg % nm, nt = wg / nm;
  const int tid = threadIdx.x, lane = tid & 63, w = tid >> 6;
  const int wr = w >> 1, wc = w & 1;
  const short* Ab = A + (size_t)(mt * 128) * K;
  const short* Bb = Bt + (size_t)(nt * 128) * K;
  f32x4 acc[4][4] = {};
  const int lrow = lane >> 3, lseg = lane & 7;

  for (int kt = 0; kt < K; kt += 64) {
#pragma unroll
    for (int s = 0; s < 4; ++s) {
      int chunk = s * 4 + w;                // wave-uniform LDS base
      int r = chunk * 8 + lrow;
      GLOAD_LDS16(Ab + (size_t)r * K + kt + lseg * 8, &Al[chunk * 512]);
      GLOAD_LDS16(Bb + (size_t)r * K + kt + lseg * 8, &Bl[chunk * 512]);
    }
    __syncthreads();
#pragma unroll
    for (int kk = 0; kk < 2; ++kk) {
      short8 af[4], bfr[4];
#pragma unroll
      for (int i = 0; i < 4; ++i) {
        af[i]  = *(const short8*)&Al[(wr * 64 + i * 16 + (lane & 15)) * 64 + kk * 32 + (lane >> 4) * 8];
        bfr[i] = *(const short8*)&Bl[(wc * 64 + i * 16 + (lane & 15)) * 64 + kk * 32 + (lane >> 4) * 8];
      }
#pragma unroll
      for (int i = 0; i < 4; ++i)
#pragma unroll
        for (int j = 0; j < 4; ++j)
          acc[i][j] = __builtin_amdgcn_mfma_f32_16x16x32_bf16(af[i], bfr[j], acc[i][j], 0, 0, 0);
    }
    __syncthreads();
  }

  const int r0 = mt * 128 + wr * 64, c0n = nt * 128 + wc * 64;
#pragma unroll
  for (int i = 0; i < 4; ++i) {
#pragma unroll
    for (int j = 0; j < 4; ++j) {
      int col = c0n + j * 16 + (lane & 15);
      float bv = bias[col];
#pragma unroll
      for (int r = 0; r < 4; ++r) {
        int row = r0 + i * 16 + (lane >> 4) * 4 + r;
        C[(size_t)row * N + col] = f2bf(acc[i][j][r] + bv);
      }
    }
  }
}

// ---------------- persistent bidirectional scan, TAGGED-WORD fat-WG ----------
// 128 WGs x 512 threads (plain launch). WG = (dir = blk>>6, wid = blk&63) owns
// h-cols [wid*16, wid*16+16) == 64 gate rows. K split 8 ways across waves.
// PROTOCOL: u64 h-word = 3 bf16 + 16-bit step tag (bits 48-63). The store IS
// the publication; the load IS the poll (retry until all 24 words/lane have
// tag == ts+1). One coherence-point round trip replaces r8's three (h-ack,
// seq publish, seq discovery). Skew<=1: a WG stores tag ts+2 only after
// validating ALL tag-(ts+1) words, i.e. after every WG finished reading tag-ts
// words => overwrite of tag-ts parity block is safe. Cross-layer stale tags
// removed by k_zero_h between layers (tag 0 never expected).
// hbuf: [parity][dir] blocks of 12288 u64; group g (0..127) covers cols
// 8g..8g+7 of batch row b: words (b*128+g)*3 + {0,1,2}:
//   w0 = c0|c1<<16|c2<<32|tag<<48
//   w1 = c3|c4<<16|c5<<32|tag<<48
//   w2 = c6|c7<<16|        tag<<48
template <bool LAST>
__global__ void __launch_bounds__(512, 1) k_scan(
    const short* __restrict__ gx,     // [16384][8192] bf16 (bias included)
    const short* __restrict__ whh,    // [8192][1024] bf16 (fwd rows 0:4096, rev 4096:8192)
    const float* __restrict__ h0,     // [6][32][1024]
    const float* __restrict__ c0,
    u64* __restrict__ hbuf,           // [2 parity][2 dir][12288] tagged words
    void* __restrict__ yout,          // bf16 [512][32][2048] or f32 (LAST)
    int layer)
{
  const int tid = threadIdx.x, lane = tid & 63, kq = tid >> 6;   // 8 waves = k-eighths
  const int dir = blockIdx.x >> 6, wid = blockIdx.x & 63;
  const int hc0 = wid * 16;
  extern __shared__ float part[];           // [8][64][35]

  // --- weights: wave kq, gate ni(0..3): B-frag col = ni*1024 + hc0 + (lane&15),
  //     k = kq*128 + ks*32 + (lane>>4)*8 ---
  short8 wfr[16];
#pragma unroll
  for (int ni = 0; ni < 4; ++ni) {
    const int grow = dir * 4096 + ni * 1024 + hc0 + (lane & 15);
    const short* wp = whh + (size_t)grow * 1024 + kq * 128 + (lane >> 4) * 8;
#pragma unroll
    for (int ks = 0; ks < 4; ++ks) wfr[ni * 4 + ks] = *(const short8*)(wp + ks * 32);
  }
#pragma unroll
  for (int i = 0; i < 16; ++i) asm volatile("" : "+v"(wfr[i]));

  // --- state init: 128 active threads, each owns (batch b4, 4 h-cols) ---
  const int b4 = tid >> 2, cg = tid & 3, col0 = hc0 + cg * 4;
  const int g_own = wid * 2 + (cg >> 1);    // this thread's 8-col group
  float ca[4] = {0.f, 0.f, 0.f, 0.f};
  short4v pgi, pgf, pgg, pgo;               // prefetched gx for the upcoming step
  if (tid < 128) {
    const int sidx = ((2 * layer + dir) * 32 + b4) * 1024 + col0;
    float4 cv = *(const float4*)(c0 + sidx);
    ca[0] = cv.x; ca[1] = cv.y; ca[2] = cv.z; ca[3] = cv.w;
    float4 hv = *(const float4*)(h0 + sidx);
    union { u64 u; short s[4]; } pk;
    pk.s[0] = f2bf(hv.x); pk.s[1] = f2bf(hv.y); pk.s[2] = f2bf(hv.z); pk.s[3] = f2bf(hv.w);
    unsigned oddlo = (unsigned)__shfl_xor((int)(unsigned)pk.u, 1);
    const u64 tagw = 1ull << 48;            // tag 1, parity 1
    u64* wb = hbuf + (size_t)(1 * 2 + dir) * 12288 + ((size_t)b4 * 128 + g_own) * 3;
    if ((cg & 1) == 0) {
      __hip_atomic_store(wb,     (pk.u & 0x0000ffffffffffffull) | tagw,
                         __ATOMIC_RELAXED, __HIP_MEMORY_SCOPE_AGENT);
      __hip_atomic_store(wb + 1, (pk.u >> 48) | ((u64)oddlo << 16) | tagw,
                         __ATOMIC_RELAXED, __HIP_MEMORY_SCOPE_AGENT);
    } else {
      __hip_atomic_store(wb + 2, ((pk.u >> 32) & 0xffffffffull) | tagw,
                         __ATOMIC_RELAXED, __HIP_MEMORY_SCOPE_AGENT);
    }
    const int t0 = dir ? 511 : 0;
    const short* gp = gx + ((size_t)(t0 * 32 + b4)) * 8192 + dir * 4096 + col0;
    pgi = *(const short4v*)(gp);
    pgf = *(const short4v*)(gp + 1024);
    pgg = *(const short4v*)(gp + 2048);
    pgo = *(const short4v*)(gp + 3072);
  }

  for (int ts = 0; ts < 512; ++ts) {
    const int t = dir ? (511 - ts) : ts;

    // --- poll+load+unpack: the data load IS the synchronization ---
    short8 af[8];
    {
      const unsigned tg = (unsigned)(ts + 1);
      const u64* hbp = hbuf + (size_t)(((ts + 1) & 1) * 2 + dir) * 12288;
      while (true) {
        int ok = 1;
#pragma unroll
        for (int mi = 0; mi < 2; ++mi) {
#pragma unroll
          for (int ks = 0; ks < 4; ++ks) {
            const int row = mi * 16 + (lane & 15);
            const int g   = kq * 16 + ks * 4 + (lane >> 4);
            const u64* wp = hbp + ((size_t)row * 128 + g) * 3;
            u64 q0 = __hip_atomic_load(wp,     __ATOMIC_RELAXED, __HIP_MEMORY_SCOPE_AGENT);
            u64 q1 = __hip_atomic_load(wp + 1, __ATOMIC_RELAXED, __HIP_MEMORY_SCOPE_AGENT);
            u64 q2 = __hip_atomic_load(wp + 2, __ATOMIC_RELAXED, __HIP_MEMORY_SCOPE_AGENT);
            ok &= (int)(((unsigned)(q0 >> 48) == tg) & ((unsigned)(q1 >> 48) == tg) &
                        ((unsigned)(q2 >> 48) == tg));
            union { unsigned u[4]; short8 v; } fu;
            unsigned b0 = (unsigned)q1;
            fu.u[0] = (unsigned)q0;                                   // h0 h1
            fu.u[1] = ((unsigned)(q0 >> 32) & 0xffffu) | (b0 << 16);  // h2 h3
            fu.u[2] = (b0 >> 16) | ((unsigned)(q1 >> 32) << 16);      // h4 h5
            fu.u[3] = (unsigned)q2;                                   // h6 h7
            af[mi * 4 + ks] = fu.v;
          }
        }
        if (__all(ok)) break;
        __builtin_amdgcn_s_sleep(1);
      }
    }

    // --- partial gates for this k-eighth: 2 m-tiles x 4 gates ---
    f32x4 acc[2][4] = {};
#pragma unroll
    for (int ks = 0; ks < 4; ++ks) {
#pragma unroll
      for (int mi = 0; mi < 2; ++mi)
#pragma unroll
        for (int ni = 0; ni < 4; ++ni)
          acc[mi][ni] = __builtin_amdgcn_mfma_f32_16x16x32_bf16(
              af[mi * 4 + ks], wfr[ni * 4 + ks], acc[mi][ni], 0, 0, 0);
    }
#pragma unroll
    for (int mi = 0; mi < 2; ++mi)
#pragma unroll
      for (int ni = 0; ni < 4; ++ni)
#pragma unroll
        for (int r = 0; r < 4; ++r)
          part[(kq * 64 + ni * 16 + (lane & 15)) * 35 + mi * 16 + (lane >> 4) * 4 + r] = acc[mi][ni][r];
    __syncthreads();

    // --- update + PUBLISH first (critical chain), then y/prefetch ---
    if (tid < 128) {
      const int c7 = cg * 4;
      float hv[4];
      union { u64 u; short s[4]; } pk;
#pragma unroll
      for (int j = 0; j < 4; ++j) {
        float gi = bf2f(pgi[j]), gf = bf2f(pgf[j]), gg = bf2f(pgg[j]), go = bf2f(pgo[j]);
#pragma unroll
        for (int q = 0; q < 8; ++q) {
          gi += part[(q * 64      + c7 + j) * 35 + b4];
          gf += part[(q * 64 + 16 + c7 + j) * 35 + b4];
          gg += part[(q * 64 + 32 + c7 + j) * 35 + b4];
          go += part[(q * 64 + 48 + c7 + j) * 35 + b4];
        }
        float i_ = fminf(fmaxf(0.2f * gi + 0.5f, 0.f), 1.f);
        float f_ = fminf(fmaxf(0.2f * gf + 0.5f, 0.f), 1.f);
        float g_ = fminf(fmaxf(gg, -1.f), 1.f);
        float o_ = fminf(fmaxf(0.2f * go + 0.5f, 0.f), 1.f);
        float cc = f_ * ca[j] + i_ * g_;
        ca[j] = cc;
        hv[j] = o_ * fminf(fmaxf(cc, -1.f), 1.f);
        pk.s[j] = f2bf(hv[j]);
      }
      const unsigned tp = (unsigned)(ts + 2);
      const u64 tagw = (u64)tp << 48;
      unsigned oddlo = (unsigned)__shfl_xor((int)(unsigned)pk.u, 1);
      u64* wb = hbuf + (size_t)((tp & 1) * 2 + dir) * 12288 + ((size_t)b4 * 128 + g_own) * 3;
      if ((cg & 1) == 0) {
        __hip_atomic_store(wb,     (pk.u & 0x0000ffffffffffffull) | tagw,
                           __ATOMIC_RELAXED, __HIP_MEMORY_SCOPE_AGENT);
        __hip_atomic_store(wb + 1, (pk.u >> 48) | ((u64)oddlo << 16) | tagw,
                           __ATOMIC_RELAXED, __HIP_MEMORY_SCOPE_AGENT);
      } else {
        __hip_atomic_store(wb + 2, ((pk.u >> 32) & 0xffffffffull) | tagw,
                           __ATOMIC_RELAXED, __HIP_MEMORY_SCOPE_AGENT);
      }
      // y-store + next gx prefetch: off the critical path
      size_t yi = ((size_t)(t * 32 + b4)) * 2048 + dir * 1024 + col0;
      if (LAST) {
        float4 f4; f4.x = hv[0]; f4.y = hv[1]; f4.z = hv[2]; f4.w = hv[3];
        *(float4*)((float*)yout + yi) = f4;
      } else {
        short4v ys; ys.x = pk.s[0]; ys.y = pk.s[1]; ys.z = pk.s[2]; ys.w = pk.s[3];
        *(short4v*)((short*)yout + yi) = ys;
      }
      if (ts < 511) {
        const int tn = dir ? (511 - (ts + 1)) : (ts + 1);
        const short* gp = gx + ((size_t)(tn * 32 + b4)) * 8192 + dir * 4096 + col0;
        pgi = *(const short4v*)(gp);
        pgf = *(const short4v*)(gp + 1024);
        pgg = *(const short4v*)(gp + 2048);
        pgo = *(const short4v*)(gp + 3072);
      }
    }
    __syncthreads();                        // release part for next step's writes
  }
}

// ---------------- host ----------------
extern "C" void kernel_launch(void* const* d_in, const int* in_sizes, int n_in,
                              void* d_out, int out_size, void* d_ws, size_t ws_size,
                              hipStream_t stream)
{
  const float* x  = (const float*)d_in[0];
  const float* h0 = (const float*)d_in[1];
  const float* c0 = (const float*)d_in[2];
  auto W = [&](int l, int d, int k) { return (const float*)d_in[3 + l * 8 + d * 4 + k]; };
  // k: 0=w_ih, 1=w_hh, 2=b_ih, 3=b_hh

  char* base = (char*)d_ws;
  size_t off = 0;
  auto alloc = [&](size_t bytes) {
    void* p = base + off;
    off = (off + bytes + 255) & ~(size_t)255;
    return p;
  };
  short* xb    = (short*)alloc(16384ull * 320 * 2);
  short* wih0  = (short*)alloc(8192ull * 320 * 2);
  short* wih1  = (short*)alloc(8192ull * 2048 * 2);
  short* wih2  = (short*)alloc(8192ull * 2048 * 2);
  short* whh0  = (short*)alloc(8192ull * 1024 * 2);
  short* whh1  = (short*)alloc(8192ull * 1024 * 2);
  short* whh2  = (short*)alloc(8192ull * 1024 * 2);
  float* bias0 = (float*)alloc(8192ull * 4);
  float* bias1 = (float*)alloc(8192ull * 4);
  float* bias2 = (float*)alloc(8192ull * 4);
  short* gx    = (short*)alloc(16384ull * 8192 * 2);
  short* y1    = (short*)alloc(16384ull * 2048 * 2);
  short* y2    = (short*)alloc(16384ull * 2048 * 2);
  u64*   hbuf  = (u64*)alloc(4ull * 12288 * 8);    // [2 parity][2 dir][12288]
  (void)ws_size; (void)in_sizes; (void)n_in; (void)out_size;

  auto cvt = [&](const float* s, short* d, size_t n) {
    size_t want = (n / 4 + 255) / 256;
    int blocks = (int)(want > 2048 ? 2048 : want);
    k_cvt<<<dim3(blocks), dim3(256), 0, stream>>>(s, d, (int)n);
  };

  cvt(x, xb, 16384ull * 320);
  short* wihs[3] = { wih0, wih1, wih2 };
  short* whhs[3] = { whh0, whh1, whh2 };
  float* biases[3] = { bias0, bias1, bias2 };
  for (int l = 0; l < 3; ++l) {
    size_t kin = (l == 0) ? 320 : 2048;
    cvt(W(l, 0, 0), wihs[l],                  4096 * kin);
    cvt(W(l, 1, 0), wihs[l] + 4096 * kin,     4096 * kin);
    cvt(W(l, 0, 1), whhs[l],                  4096ull * 1024);
    cvt(W(l, 1, 1), whhs[l] + 4096ull * 1024, 4096ull * 1024);
    k_bias<<<dim3(32), dim3(256), 0, stream>>>(W(l, 0, 2), W(l, 0, 3), W(l, 1, 2), W(l, 1, 3), biases[l]);
  }

  const int M = 16384, N = 8192;
  const int LDSB = 8 * 64 * 35 * 4;         // 71680 B dynamic LDS

  // ---- layer 0 ----
  k_gemm<<<dim3((M / 128) * (N / 128)), dim3(256), 0, stream>>>(xb, wih0, bias0, gx, M, N, 320);
  k_zero_h<<<dim3(192), dim3(256), 0, stream>>>(hbuf);
  k_scan<false><<<dim3(128), dim3(512), LDSB, stream>>>(gx, whh0, h0, c0, hbuf, (void*)y1, 0);
  // ---- layer 1 ----
  k_gemm<<<dim3((M / 128) * (N / 128)), dim3(256), 0, stream>>>(y1, wih1, bias1, gx, M, N, 2048);
  k_zero_h<<<dim3(192), dim3(256), 0, stream>>>(hbuf);
  k_scan<false><<<dim3(128), dim3(512), LDSB, stream>>>(gx, whh1, h0, c0, hbuf, (void*)y2, 1);
  // ---- layer 2 ----
  k_gemm<<<dim3((M / 128) * (N / 128)), dim3(256), 0, stream>>>(y2, wih2, bias2, gx, M, N, 2048);
  k_zero_h<<<dim3(192), dim3(256), 0, stream>>>(hbuf);
  k_scan<true><<<dim3(128), dim3(512), LDSB, stream>>>(gx, whh2, h0, c0, hbuf, d_out, 2);
}

// Round 10
// 14999.422 us; speedup vs baseline: 1.1872x; 1.1872x over previous
//
#include <hip/hip_runtime.h>

typedef __attribute__((ext_vector_type(8))) short short8;
typedef __attribute__((ext_vector_type(4))) short short4v;
typedef __attribute__((ext_vector_type(4))) float f32x4;
typedef unsigned long long u64;

__device__ __forceinline__ short f2bf(float x) {
  union { float f; unsigned u; } v; v.f = x;
  unsigned r = v.u + 0x7fffu + ((v.u >> 16) & 1u);   // RNE
  return (short)(r >> 16);
}
__device__ __forceinline__ float bf2f(short b) {
  union { unsigned u; float f; } v; v.u = ((unsigned)(unsigned short)b) << 16;
  return v.f;
}

#define GLOAD_LDS16(g, l) __builtin_amdgcn_global_load_lds( \
    (const __attribute__((address_space(1))) void*)(g),     \
    (__attribute__((address_space(3))) void*)(l), 16, 0, 0)

// ---------------- f32 -> bf16 conversion ----------------
__global__ void k_cvt(const float* __restrict__ s, short* __restrict__ d, int n) {
  int stride = gridDim.x * blockDim.x * 4;
  for (int i = (blockIdx.x * blockDim.x + threadIdx.x) * 4; i < n; i += stride) {
    float4 v = *(const float4*)(s + i);
    short4v o;
    o.x = f2bf(v.x); o.y = f2bf(v.y); o.z = f2bf(v.z); o.w = f2bf(v.w);
    *(short4v*)(d + i) = o;
  }
}

// ---------------- combined bias (fwd 0:4096, rev 4096:8192) ----------------
__global__ void k_bias(const float* __restrict__ bif, const float* __restrict__ bhf,
                       const float* __restrict__ bir, const float* __restrict__ bhr,
                       float* __restrict__ o) {
  int i = blockIdx.x * 256 + threadIdx.x;
  o[i] = (i < 4096) ? (bif[i] + bhf[i]) : (bir[i - 4096] + bhr[i - 4096]);
}

// ---------------- zero tagged h buffer + seq hints (53248 u64) ----------------
__global__ void k_zero_h(u64* __restrict__ p) { p[blockIdx.x * 256 + threadIdx.x] = 0; }

// ---------------- input GEMM: C[M][N] = A[M][K] * Bt[N][K]^T + bias, bf16 out ----
__global__ void __launch_bounds__(256) k_gemm(
    const short* __restrict__ A, const short* __restrict__ Bt,
    const float* __restrict__ bias, short* __restrict__ C,
    int M, int N, int K)
{
  __shared__ short Al[128 * 64];
  __shared__ short Bl[128 * 64];
  const int nm = M >> 7;
  int wg = blockIdx.x;
  int q = gridDim.x >> 3;                   // gridDim.x % 8 == 0 (8192)
  wg = (wg & 7) * q + (wg >> 3);            // XCD-aware swizzle (bijective)
  const int mt = wg % nm, nt = wg / nm;
  const int tid = threadIdx.x, lane = tid & 63, w = tid >> 6;
  const int wr = w >> 1, wc = w & 1;
  const short* Ab = A + (size_t)(mt * 128) * K;
  const short* Bb = Bt + (size_t)(nt * 128) * K;
  f32x4 acc[4][4] = {};
  const int lrow = lane >> 3, lseg = lane & 7;

  for (int kt = 0; kt < K; kt += 64) {
#pragma unroll
    for (int s = 0; s < 4; ++s) {
      int chunk = s * 4 + w;                // wave-uniform LDS base
      int r = chunk * 8 + lrow;
      GLOAD_LDS16(Ab + (size_t)r * K + kt + lseg * 8, &Al[chunk * 512]);
      GLOAD_LDS16(Bb + (size_t)r * K + kt + lseg * 8, &Bl[chunk * 512]);
    }
    __syncthreads();
#pragma unroll
    for (int kk = 0; kk < 2; ++kk) {
      short8 af[4], bfr[4];
#pragma unroll
      for (int i = 0; i < 4; ++i) {
        af[i]  = *(const short8*)&Al[(wr * 64 + i * 16 + (lane & 15)) * 64 + kk * 32 + (lane >> 4) * 8];
        bfr[i] = *(const short8*)&Bl[(wc * 64 + i * 16 + (lane & 15)) * 64 + kk * 32 + (lane >> 4) * 8];
      }
#pragma unroll
      for (int i = 0; i < 4; ++i)
#pragma unroll
        for (int j = 0; j < 4; ++j)
          acc[i][j] = __builtin_amdgcn_mfma_f32_16x16x32_bf16(af[i], bfr[j], acc[i][j], 0, 0, 0);
    }
    __syncthreads();
  }

  const int r0 = mt * 128 + wr * 64, c0n = nt * 128 + wc * 64;
#pragma unroll
  for (int i = 0; i < 4; ++i) {
#pragma unroll
    for (int j = 0; j < 4; ++j) {
      int col = c0n + j * 16 + (lane & 15);
      float bv = bias[col];
#pragma unroll
      for (int r = 0; r < 4; ++r) {
        int row = r0 + i * 16 + (lane >> 4) * 4 + r;
        C[(size_t)row * N + col] = f2bf(acc[i][j][r] + bv);
      }
    }
  }
}

// ---------------- persistent bidirectional scan: tags + seq-hint + per-wave gate
// 128 WGs x 512 threads (plain launch). WG = (dir=blk>>6, wid=blk&63) owns h-cols
// [wid*16, wid*16+16) == 64 gate rows. K split 8 ways across waves.
// PROTOCOL: u64 h-word = 3 bf16 + tag (bits 48-63). Producer: tagged stores,
// then (NO vmcnt ack) a per-half seq HINT (seq[wid*2+half] = tag just stored).
// Consumer wave kq: cheap-spin its 16 hint lines >= ts+1, then ONE 24-word
// batch load validating every tag == ts+1 (retry rare; validation is the
// correctness guarantee, the hint only prevents r9's expensive early spinning).
// Per-wave gating: wave kq depends only on producer WGs [kq*8, kq*8+8); it
// loads + MFMAs as soon as THEY are done (no WG-wide poll-join barrier).
// Skew<=1 safety: the update phase is behind a barrier over all 8 waves which
// collectively validated ALL 64 producers' tag ts+1 => publishing tag ts+2
// (destroying tag ts) happens only after every WG finished reading tag ts.
// hbuf: [parity][dir] x 12288 u64; group g(0..127) row b: (b*128+g)*3 + {0,1,2}
//   w0=c0|c1<<16|c2<<32|tag<<48  w1=c3|c4<<16|c5<<32|tag<<48  w2=c6|c7<<16|tag<<48
// seq hints: int lines at hbuf+49152, [dir][128 lines] @ 32-int stride.
template <bool LAST>
__global__ void __launch_bounds__(512, 1) k_scan(
    const short* __restrict__ gx,     // [16384][8192] bf16 (bias included)
    const short* __restrict__ whh,    // [8192][1024] bf16 (fwd rows 0:4096, rev 4096:8192)
    const float* __restrict__ h0,     // [6][32][1024]
    const float* __restrict__ c0,
    u64* __restrict__ hbuf,
    void* __restrict__ yout,          // bf16 [512][32][2048] or f32 (LAST)
    int layer)
{
  const int tid = threadIdx.x, lane = tid & 63, kq = tid >> 6;   // 8 waves = k-eighths
  const int dir = blockIdx.x >> 6, wid = blockIdx.x & 63;
  const int hc0 = wid * 16;
  extern __shared__ float part[];           // [8][32][68]: [kq][batch][gaterow]
  int* seq = (int*)(hbuf + 49152) + dir * 4096;

  // --- weights: wave kq, gate ni(0..3): col = hc0+(lane&15), k = kq*128+ks*32+(lane>>4)*8
  short8 wfr[16];
#pragma unroll
  for (int ni = 0; ni < 4; ++ni) {
    const int grow = dir * 4096 + ni * 1024 + hc0 + (lane & 15);
    const short* wp = whh + (size_t)grow * 1024 + kq * 128 + (lane >> 4) * 8;
#pragma unroll
    for (int ks = 0; ks < 4; ++ks) wfr[ni * 4 + ks] = *(const short8*)(wp + ks * 32);
  }
#pragma unroll
  for (int i = 0; i < 16; ++i) asm volatile("" : "+v"(wfr[i]));

  // --- state init: 128 active threads, each owns (batch b4, 4 h-cols) ---
  const int b4 = tid >> 2, cg = tid & 3, col0 = hc0 + cg * 4;
  const int g_own = wid * 2 + (cg >> 1);
  float ca[4] = {0.f, 0.f, 0.f, 0.f};
  short4v pgi, pgf, pgg, pgo;
  if (tid < 128) {
    const int sidx = ((2 * layer + dir) * 32 + b4) * 1024 + col0;
    float4 cv = *(const float4*)(c0 + sidx);
    ca[0] = cv.x; ca[1] = cv.y; ca[2] = cv.z; ca[3] = cv.w;
    float4 hv = *(const float4*)(h0 + sidx);
    union { u64 u; short s[4]; } pk;
    pk.s[0] = f2bf(hv.x); pk.s[1] = f2bf(hv.y); pk.s[2] = f2bf(hv.z); pk.s[3] = f2bf(hv.w);
    unsigned oddlo = (unsigned)__shfl_xor((int)(unsigned)pk.u, 1);
    const u64 tagw = 1ull << 48;            // tag 1, parity 1
    u64* wb = hbuf + (size_t)(1 * 2 + dir) * 12288 + ((size_t)b4 * 128 + g_own) * 3;
    if ((cg & 1) == 0) {
      __hip_atomic_store(wb,     (pk.u & 0x0000ffffffffffffull) | tagw,
                         __ATOMIC_RELAXED, __HIP_MEMORY_SCOPE_AGENT);
      __hip_atomic_store(wb + 1, (pk.u >> 48) | ((u64)oddlo << 16) | tagw,
                         __ATOMIC_RELAXED, __HIP_MEMORY_SCOPE_AGENT);
    } else {
      __hip_atomic_store(wb + 2, ((pk.u >> 32) & 0xffffffffull) | tagw,
                         __ATOMIC_RELAXED, __HIP_MEMORY_SCOPE_AGENT);
    }
    if ((tid & 63) == 0)                    // hint: half (tid>>6) of WG wid done
      __hip_atomic_store(seq + (wid * 2 + (tid >> 6)) * 32, 1,
                         __ATOMIC_RELAXED, __HIP_MEMORY_SCOPE_AGENT);
    const int t0 = dir ? 511 : 0;
    const short* gp = gx + ((size_t)(t0 * 32 + b4)) * 8192 + dir * 4096 + col0;
    pgi = *(const short4v*)(gp);
    pgf = *(const short4v*)(gp + 1024);
    pgg = *(const short4v*)(gp + 2048);
    pgo = *(const short4v*)(gp + 3072);
  }

  for (int ts = 0; ts < 512; ++ts) {
    const int t = dir ? (511 - ts) : ts;
    const unsigned tg = (unsigned)(ts + 1);
    const u64* hbp = hbuf + (size_t)((tg & 1) * 2 + dir) * 12288;

    // --- A) cheap hint spin: wave kq's 16 producer lines ---
    if (lane < 16) {
      int* sp = seq + (kq * 16 + lane) * 32;
      while (__hip_atomic_load(sp, __ATOMIC_RELAXED, __HIP_MEMORY_SCOPE_AGENT) < (int)tg)
        __builtin_amdgcn_s_sleep(1);
    }
    asm volatile("" ::: "memory");

    // --- B) one batch load + tag validation (retry rare) ---
    short8 af[8];
    while (true) {
      int ok = 1;
#pragma unroll
      for (int mi = 0; mi < 2; ++mi) {
#pragma unroll
        for (int ks = 0; ks < 4; ++ks) {
          const int row = mi * 16 + (lane & 15);
          const int g   = kq * 16 + ks * 4 + (lane >> 4);
          const u64* wp = hbp + ((size_t)row * 128 + g) * 3;
          u64 q0 = __hip_atomic_load(wp,     __ATOMIC_RELAXED, __HIP_MEMORY_SCOPE_AGENT);
          u64 q1 = __hip_atomic_load(wp + 1, __ATOMIC_RELAXED, __HIP_MEMORY_SCOPE_AGENT);
          u64 q2 = __hip_atomic_load(wp + 2, __ATOMIC_RELAXED, __HIP_MEMORY_SCOPE_AGENT);
          ok &= (int)(((unsigned)(q0 >> 48) == tg) & ((unsigned)(q1 >> 48) == tg) &
                      ((unsigned)(q2 >> 48) == tg));
          union { unsigned u[4]; short8 v; } fu;
          unsigned b0 = (unsigned)q1;
          fu.u[0] = (unsigned)q0;                                   // h0 h1
          fu.u[1] = ((unsigned)(q0 >> 32) & 0xffffu) | (b0 << 16);  // h2 h3
          fu.u[2] = (b0 >> 16) | ((unsigned)(q1 >> 32) << 16);      // h4 h5
          fu.u[3] = (unsigned)q2;                                   // h6 h7
          af[mi * 4 + ks] = fu.v;
        }
      }
      if (__all(ok)) break;
      __builtin_amdgcn_s_sleep(4);
    }
#pragma unroll
    for (int i = 0; i < 8; ++i) asm volatile("" : "+v"(af[i]));

    // --- C) partial gates: 2 m-tiles x 4 gates ---
    f32x4 acc[2][4] = {};
#pragma unroll
    for (int ks = 0; ks < 4; ++ks) {
#pragma unroll
      for (int mi = 0; mi < 2; ++mi)
#pragma unroll
        for (int ni = 0; ni < 4; ++ni)
          acc[mi][ni] = __builtin_amdgcn_mfma_f32_16x16x32_bf16(
              af[mi * 4 + ks], wfr[ni * 4 + ks], acc[mi][ni], 0, 0, 0);
    }
    // --- D) transposed partials: part[kq][batch][gaterow], stride 68 ---
#pragma unroll
    for (int mi = 0; mi < 2; ++mi)
#pragma unroll
      for (int ni = 0; ni < 4; ++ni)
#pragma unroll
        for (int r = 0; r < 4; ++r)
          part[(kq * 32 + mi * 16 + (lane >> 4) * 4 + r) * 68 + ni * 16 + (lane & 15)] = acc[mi][ni][r];
    __syncthreads();

    // --- F) update: vector reduce (32 x b128), activate, publish, y, prefetch ---
    if (tid < 128) {
      f32x4 sI = {}, sF = {}, sG = {}, sO = {};
#pragma unroll
      for (int q = 0; q < 8; ++q) {
        const int base = (q * 32 + b4) * 68 + cg * 4;
        sI += *(const f32x4*)&part[base];
        sF += *(const f32x4*)&part[base + 16];
        sG += *(const f32x4*)&part[base + 32];
        sO += *(const f32x4*)&part[base + 48];
      }
      float hv[4];
      union { u64 u; short s[4]; } pk;
#pragma unroll
      for (int j = 0; j < 4; ++j) {
        float gi = sI[j] + bf2f(pgi[j]);
        float gf = sF[j] + bf2f(pgf[j]);
        float gg = sG[j] + bf2f(pgg[j]);
        float go = sO[j] + bf2f(pgo[j]);
        float i_ = fminf(fmaxf(0.2f * gi + 0.5f, 0.f), 1.f);
        float f_ = fminf(fmaxf(0.2f * gf + 0.5f, 0.f), 1.f);
        float g_ = fminf(fmaxf(gg, -1.f), 1.f);
        float o_ = fminf(fmaxf(0.2f * go + 0.5f, 0.f), 1.f);
        float cc = f_ * ca[j] + i_ * g_;
        ca[j] = cc;
        hv[j] = o_ * fminf(fmaxf(cc, -1.f), 1.f);
        pk.s[j] = f2bf(hv[j]);
      }
      const unsigned tp = (unsigned)(ts + 2);
      const u64 tagw = (u64)tp << 48;
      unsigned oddlo = (unsigned)__shfl_xor((int)(unsigned)pk.u, 1);
      u64* wb = hbuf + (size_t)((tp & 1) * 2 + dir) * 12288 + ((size_t)b4 * 128 + g_own) * 3;
      if ((cg & 1) == 0) {
        __hip_atomic_store(wb,     (pk.u & 0x0000ffffffffffffull) | tagw,
                           __ATOMIC_RELAXED, __HIP_MEMORY_SCOPE_AGENT);
        __hip_atomic_store(wb + 1, (pk.u >> 48) | ((u64)oddlo << 16) | tagw,
                           __ATOMIC_RELAXED, __HIP_MEMORY_SCOPE_AGENT);
      } else {
        __hip_atomic_store(wb + 2, ((pk.u >> 32) & 0xffffffffull) | tagw,
                           __ATOMIC_RELAXED, __HIP_MEMORY_SCOPE_AGENT);
      }
      if ((tid & 63) == 0)                  // hint AFTER this wave's h stores issued
        __hip_atomic_store(seq + (wid * 2 + (tid >> 6)) * 32, (int)tp,
                           __ATOMIC_RELAXED, __HIP_MEMORY_SCOPE_AGENT);
      // y store + next gx prefetch: off the critical path
      size_t yi = ((size_t)(t * 32 + b4)) * 2048 + dir * 1024 + col0;
      if (LAST) {
        float4 f4; f4.x = hv[0]; f4.y = hv[1]; f4.z = hv[2]; f4.w = hv[3];
        *(float4*)((float*)yout + yi) = f4;
      } else {
        short4v ys; ys.x = pk.s[0]; ys.y = pk.s[1]; ys.z = pk.s[2]; ys.w = pk.s[3];
        *(short4v*)((short*)yout + yi) = ys;
      }
      if (ts < 511) {
        const int tn = dir ? (511 - (ts + 1)) : (ts + 1);
        const short* gp = gx + ((size_t)(tn * 32 + b4)) * 8192 + dir * 4096 + col0;
        pgi = *(const short4v*)(gp);
        pgf = *(const short4v*)(gp + 1024);
        pgg = *(const short4v*)(gp + 2048);
        pgo = *(const short4v*)(gp + 3072);
      }
    }
    __syncthreads();                        // release part for next step's writes
  }
}

// ---------------- host ----------------
extern "C" void kernel_launch(void* const* d_in, const int* in_sizes, int n_in,
                              void* d_out, int out_size, void* d_ws, size_t ws_size,
                              hipStream_t stream)
{
  const float* x  = (const float*)d_in[0];
  const float* h0 = (const float*)d_in[1];
  const float* c0 = (const float*)d_in[2];
  auto W = [&](int l, int d, int k) { return (const float*)d_in[3 + l * 8 + d * 4 + k]; };
  // k: 0=w_ih, 1=w_hh, 2=b_ih, 3=b_hh

  char* base = (char*)d_ws;
  size_t off = 0;
  auto alloc = [&](size_t bytes) {
    void* p = base + off;
    off = (off + bytes + 255) & ~(size_t)255;
    return p;
  };
  short* xb    = (short*)alloc(16384ull * 320 * 2);
  short* wih0  = (short*)alloc(8192ull * 320 * 2);
  short* wih1  = (short*)alloc(8192ull * 2048 * 2);
  short* wih2  = (short*)alloc(8192ull * 2048 * 2);
  short* whh0  = (short*)alloc(8192ull * 1024 * 2);
  short* whh1  = (short*)alloc(8192ull * 1024 * 2);
  short* whh2  = (short*)alloc(8192ull * 1024 * 2);
  float* bias0 = (float*)alloc(8192ull * 4);
  float* bias1 = (float*)alloc(8192ull * 4);
  float* bias2 = (float*)alloc(8192ull * 4);
  short* gx    = (short*)alloc(16384ull * 8192 * 2);
  short* y1    = (short*)alloc(16384ull * 2048 * 2);
  short* y2    = (short*)alloc(16384ull * 2048 * 2);
  u64*   hbuf  = (u64*)alloc(53248ull * 8);   // 4x12288 tagged words + 8192-int seq
  (void)ws_size; (void)in_sizes; (void)n_in; (void)out_size;

  auto cvt = [&](const float* s, short* d, size_t n) {
    size_t want = (n / 4 + 255) / 256;
    int blocks = (int)(want > 2048 ? 2048 : want);
    k_cvt<<<dim3(blocks), dim3(256), 0, stream>>>(s, d, (int)n);
  };

  cvt(x, xb, 16384ull * 320);
  short* wihs[3] = { wih0, wih1, wih2 };
  short* whhs[3] = { whh0, whh1, whh2 };
  float* biases[3] = { bias0, bias1, bias2 };
  for (int l = 0; l < 3; ++l) {
    size_t kin = (l == 0) ? 320 : 2048;
    cvt(W(l, 0, 0), wihs[l],                  4096 * kin);
    cvt(W(l, 1, 0), wihs[l] + 4096 * kin,     4096 * kin);
    cvt(W(l, 0, 1), whhs[l],                  4096ull * 1024);
    cvt(W(l, 1, 1), whhs[l] + 4096ull * 1024, 4096ull * 1024);
    k_bias<<<dim3(32), dim3(256), 0, stream>>>(W(l, 0, 2), W(l, 0, 3), W(l, 1, 2), W(l, 1, 3), biases[l]);
  }

  const int M = 16384, N = 8192;
  const int LDSB = 8 * 32 * 68 * 4;         // 69632 B dynamic LDS

  // ---- layer 0 ----
  k_gemm<<<dim3((M / 128) * (N / 128)), dim3(256), 0, stream>>>(xb, wih0, bias0, gx, M, N, 320);
  k_zero_h<<<dim3(208), dim3(256), 0, stream>>>(hbuf);
  k_scan<false><<<dim3(128), dim3(512), LDSB, stream>>>(gx, whh0, h0, c0, hbuf, (void*)y1, 0);
  // ---- layer 1 ----
  k_gemm<<<dim3((M / 128) * (N / 128)), dim3(256), 0, stream>>>(y1, wih1, bias1, gx, M, N, 2048);
  k_zero_h<<<dim3(208), dim3(256), 0, stream>>>(hbuf);
  k_scan<false><<<dim3(128), dim3(512), LDSB, stream>>>(gx, whh1, h0, c0, hbuf, (void*)y2, 1);
  // ---- layer 2 ----
  k_gemm<<<dim3((M / 128) * (N / 128)), dim3(256), 0, stream>>>(y2, wih2, bias2, gx, M, N, 2048);
  k_zero_h<<<dim3(208), dim3(256), 0, stream>>>(hbuf);
  k_scan<true><<<dim3(128), dim3(512), LDSB, stream>>>(gx, whh2, h0, c0, hbuf, d_out, 2);
}

// Round 12
// 12000.698 us; speedup vs baseline: 1.4839x; 1.2499x over previous
//
#include <hip/hip_runtime.h>

typedef __attribute__((ext_vector_type(8))) short short8;
typedef __attribute__((ext_vector_type(4))) short short4v;
typedef __attribute__((ext_vector_type(4))) float f32x4;
typedef unsigned long long u64;

__device__ __forceinline__ short f2bf(float x) {
  union { float f; unsigned u; } v; v.f = x;
  unsigned r = v.u + 0x7fffu + ((v.u >> 16) & 1u);   // RNE
  return (short)(r >> 16);
}
__device__ __forceinline__ float bf2f(short b) {
  union { unsigned u; float f; } v; v.u = ((unsigned)(unsigned short)b) << 16;
  return v.f;
}

#define GLOAD_LDS16(g, l) __builtin_amdgcn_global_load_lds( \
    (const __attribute__((address_space(1))) void*)(g),     \
    (__attribute__((address_space(3))) void*)(l), 16, 0, 0)

// ---------------- f32 -> bf16 conversion ----------------
__global__ void k_cvt(const float* __restrict__ s, short* __restrict__ d, int n) {
  int stride = gridDim.x * blockDim.x * 4;
  for (int i = (blockIdx.x * blockDim.x + threadIdx.x) * 4; i < n; i += stride) {
    float4 v = *(const float4*)(s + i);
    short4v o;
    o.x = f2bf(v.x); o.y = f2bf(v.y); o.z = f2bf(v.z); o.w = f2bf(v.w);
    *(short4v*)(d + i) = o;
  }
}

// ---------------- combined bias (fwd 0:4096, rev 4096:8192) ----------------
__global__ void k_bias(const float* __restrict__ bif, const float* __restrict__ bhf,
                       const float* __restrict__ bir, const float* __restrict__ bhr,
                       float* __restrict__ o) {
  int i = blockIdx.x * 256 + threadIdx.x;
  o[i] = (i < 4096) ? (bif[i] + bhf[i]) : (bir[i - 4096] + bhr[i - 4096]);
}

// ---------------- input GEMM: C[M][N] = A[M][K] * Bt[N][K]^T + bias, bf16 out ----
__global__ void __launch_bounds__(256) k_gemm(
    const short* __restrict__ A, const short* __restrict__ Bt,
    const float* __restrict__ bias, short* __restrict__ C,
    int M, int N, int K)
{
  __shared__ short Al[128 * 64];
  __shared__ short Bl[128 * 64];
  const int nm = M >> 7;
  int wg = blockIdx.x;
  int q = gridDim.x >> 3;                   // gridDim.x % 8 == 0 (8192)
  wg = (wg & 7) * q + (wg >> 3);            // XCD-aware swizzle (bijective)
  const int mt = wg % nm, nt = wg / nm;
  const int tid = threadIdx.x, lane = tid & 63, w = tid >> 6;
  const int wr = w >> 1, wc = w & 1;
  const short* Ab = A + (size_t)(mt * 128) * K;
  const short* Bb = Bt + (size_t)(nt * 128) * K;
  f32x4 acc[4][4] = {};
  const int lrow = lane >> 3, lseg = lane & 7;

  for (int kt = 0; kt < K; kt += 64) {
#pragma unroll
    for (int s = 0; s < 4; ++s) {
      int chunk = s * 4 + w;                // wave-uniform LDS base
      int r = chunk * 8 + lrow;
      GLOAD_LDS16(Ab + (size_t)r * K + kt + lseg * 8, &Al[chunk * 512]);
      GLOAD_LDS16(Bb + (size_t)r * K + kt + lseg * 8, &Bl[chunk * 512]);
    }
    __syncthreads();
#pragma unroll
    for (int kk = 0; kk < 2; ++kk) {
      short8 af[4], bfr[4];
#pragma unroll
      for (int i = 0; i < 4; ++i) {
        af[i]  = *(const short8*)&Al[(wr * 64 + i * 16 + (lane & 15)) * 64 + kk * 32 + (lane >> 4) * 8];
        bfr[i] = *(const short8*)&Bl[(wc * 64 + i * 16 + (lane & 15)) * 64 + kk * 32 + (lane >> 4) * 8];
      }
#pragma unroll
      for (int i = 0; i < 4; ++i)
#pragma unroll
        for (int j = 0; j < 4; ++j)
          acc[i][j] = __builtin_amdgcn_mfma_f32_16x16x32_bf16(af[i], bfr[j], acc[i][j], 0, 0, 0);
    }
    __syncthreads();
  }

  const int r0 = mt * 128 + wr * 64, c0n = nt * 128 + wc * 64;
#pragma unroll
  for (int i = 0; i < 4; ++i) {
#pragma unroll
    for (int j = 0; j < 4; ++j) {
      int col = c0n + j * 16 + (lane & 15);
      float bv = bias[col];
#pragma unroll
      for (int r = 0; r < 4; ++r) {
        int row = r0 + i * 16 + (lane >> 4) * 4 + r;
        C[(size_t)row * N + col] = f2bf(acc[i][j][r] + bv);
      }
    }
  }
}

// ---------------- persistent bidirectional scan: r8 protocol + L2 broadcast ---
// 128 WGs x 512 threads (plain launch). WG = (dir=blk>>6, wid=blk&63) owns h-cols
// [wid*16, wid*16+16) == 64 gate rows. K split 8 ways across waves.
// h words: u64 = 3 bf16 + tag ((layer<<10)|step, bits 48-63), stored to a
// 16-SLOT deep buffer (slot = step & 15). Producer (r8-proven): tagged atomic
// stores -> vmcnt(0) ack -> per-half seq hint. Consumer wave kq: spin its 16
// hint lines >= tag, then NORMAL b64 loads (first XCD toucher pulls MALL->L2,
// the other 15 WGs on that XCD hit local L2 -- hierarchical broadcast) + tag
// validation; mismatch (stale clean L2 line / cross-layer leftovers) falls
// back to agent-atomic reload. NO zeroing needed: consumers only accept exact
// (layer|step) tags, every slot read was freshly written this layer (slot
// (ts+1)&15 is written at step ts-1, hints are store-ack'd), and stale tags
// can only FAIL the equality check -> slow path.
// Skew: publish of step s+2 happens after the partials barrier (all 8 waves
// validated s+1 => every WG done reading s); writes land 14 slots from the
// oldest live reader. Partials: [kq][64][35] f32 (write <=2-way; reduce reads
// conflict-free: banks 3*b4 mod 32 distinct).
// NOTE ws budget: d_ws is ~512 MiB. r11 overflowed it (539 MB) -> GPU memory
// fault + abort. Fixed by aliasing y2 onto y1 (y1 dead after gemm l+1 reads it).
template <bool LAST>
__global__ void __launch_bounds__(512, 1) k_scan(
    const short* __restrict__ gx,     // [16384][8192] bf16 (bias included)
    const short* __restrict__ whh,    // [8192][1024] bf16 (fwd rows 0:4096, rev 4096:8192)
    const float* __restrict__ h0,     // [6][32][1024]
    const float* __restrict__ c0,
    u64* __restrict__ hbuf,           // [16 slot][2 dir][12288] + seq at +393216
    void* __restrict__ yout,          // bf16 [512][32][2048] or f32 (LAST)
    int layer)
{
  const int tid = threadIdx.x, lane = tid & 63, kq = tid >> 6;   // 8 waves = k-eighths
  const int dir = blockIdx.x >> 6, wid = blockIdx.x & 63;
  const int hc0 = wid * 16;
  extern __shared__ float part[];           // [8][64][35]
  int* seq = (int*)(hbuf + 393216) + dir * 4096;   // 128 lines @ 32-int stride
  const int lbase = layer << 10;

  // --- weights: wave kq, gate ni(0..3): col = hc0+(lane&15), k = kq*128+ks*32+(lane>>4)*8
  short8 wfr[16];
#pragma unroll
  for (int ni = 0; ni < 4; ++ni) {
    const int grow = dir * 4096 + ni * 1024 + hc0 + (lane & 15);
    const short* wp = whh + (size_t)grow * 1024 + kq * 128 + (lane >> 4) * 8;
#pragma unroll
    for (int ks = 0; ks < 4; ++ks) wfr[ni * 4 + ks] = *(const short8*)(wp + ks * 32);
  }
#pragma unroll
  for (int i = 0; i < 16; ++i) asm volatile("" : "+v"(wfr[i]));

  // --- state init: 128 active threads, each owns (batch b4, 4 h-cols) ---
  const int b4 = tid >> 2, cg = tid & 3, col0 = hc0 + cg * 4;
  const int g_own = wid * 2 + (cg >> 1);
  float ca[4] = {0.f, 0.f, 0.f, 0.f};
  short4v pgi, pgf, pgg, pgo;
  if (tid < 128) {
    const int sidx = ((2 * layer + dir) * 32 + b4) * 1024 + col0;
    float4 cv = *(const float4*)(c0 + sidx);
    ca[0] = cv.x; ca[1] = cv.y; ca[2] = cv.z; ca[3] = cv.w;
    float4 hv = *(const float4*)(h0 + sidx);
    union { u64 u; short s[4]; } pk;
    pk.s[0] = f2bf(hv.x); pk.s[1] = f2bf(hv.y); pk.s[2] = f2bf(hv.z); pk.s[3] = f2bf(hv.w);
    unsigned oddlo = (unsigned)__shfl_xor((int)(unsigned)pk.u, 1);
    const u64 tagw = (u64)(unsigned)(lbase | 1) << 48;           // step 1, slot 1
    u64* wb = hbuf + (size_t)(1 * 2 + dir) * 12288 + ((size_t)b4 * 128 + g_own) * 3;
    if ((cg & 1) == 0) {
      __hip_atomic_store(wb,     (pk.u & 0x0000ffffffffffffull) | tagw,
                         __ATOMIC_RELAXED, __HIP_MEMORY_SCOPE_AGENT);
      __hip_atomic_store(wb + 1, (pk.u >> 48) | ((u64)oddlo << 16) | tagw,
                         __ATOMIC_RELAXED, __HIP_MEMORY_SCOPE_AGENT);
    } else {
      __hip_atomic_store(wb + 2, ((pk.u >> 32) & 0xffffffffull) | tagw,
                         __ATOMIC_RELAXED, __HIP_MEMORY_SCOPE_AGENT);
    }
    asm volatile("s_waitcnt vmcnt(0)" ::: "memory");             // ack: h at MALL
    if ((tid & 63) == 0)
      __hip_atomic_store(seq + (wid * 2 + (tid >> 6)) * 32, lbase | 1,
                         __ATOMIC_RELAXED, __HIP_MEMORY_SCOPE_AGENT);
    const int t0 = dir ? 511 : 0;
    const short* gp = gx + ((size_t)(t0 * 32 + b4)) * 8192 + dir * 4096 + col0;
    pgi = *(const short4v*)(gp);
    pgf = *(const short4v*)(gp + 1024);
    pgg = *(const short4v*)(gp + 2048);
    pgo = *(const short4v*)(gp + 3072);
  }

  for (int ts = 0; ts < 512; ++ts) {
    const int t = dir ? (511 - ts) : ts;
    const unsigned tg = (unsigned)(lbase | (ts + 1));
    const u64* hbp = hbuf + (size_t)(((ts + 1) & 15) * 2 + dir) * 12288;

    // --- A) hint spin: wave kq's 16 producer lines (ack'd => reliable) ---
    if (lane < 16) {
      int* sp = seq + (kq * 16 + lane) * 32;
      while (__hip_atomic_load(sp, __ATOMIC_RELAXED, __HIP_MEMORY_SCOPE_AGENT) < (int)tg)
        __builtin_amdgcn_s_sleep(1);
    }
    asm volatile("" ::: "memory");

    // --- B) fast path: NORMAL loads (L2-broadcast) + tag validation ---
    short8 af[8];
    {
      int ok = 1;
#pragma unroll
      for (int mi = 0; mi < 2; ++mi) {
#pragma unroll
        for (int ks = 0; ks < 4; ++ks) {
          const int row = mi * 16 + (lane & 15);
          const int g   = kq * 16 + ks * 4 + (lane >> 4);
          const u64* wp = hbp + ((size_t)row * 128 + g) * 3;
          u64 q0 = wp[0], q1 = wp[1], q2 = wp[2];
          ok &= (int)(((unsigned)(q0 >> 48) == tg) & ((unsigned)(q1 >> 48) == tg) &
                      ((unsigned)(q2 >> 48) == tg));
          union { unsigned u[4]; short8 v; } fu;
          unsigned b0 = (unsigned)q1;
          fu.u[0] = (unsigned)q0;
          fu.u[1] = ((unsigned)(q0 >> 32) & 0xffffu) | (b0 << 16);
          fu.u[2] = (b0 >> 16) | ((unsigned)(q1 >> 32) << 16);
          fu.u[3] = (unsigned)q2;
          af[mi * 4 + ks] = fu.v;
        }
      }
      if (!__all(ok)) {
        // --- slow path (rare): agent-atomic reload until every tag matches ---
        while (true) {
          ok = 1;
#pragma unroll
          for (int mi = 0; mi < 2; ++mi) {
#pragma unroll
            for (int ks = 0; ks < 4; ++ks) {
              const int row = mi * 16 + (lane & 15);
              const int g   = kq * 16 + ks * 4 + (lane >> 4);
              const u64* wp = hbp + ((size_t)row * 128 + g) * 3;
              u64 q0 = __hip_atomic_load(wp,     __ATOMIC_RELAXED, __HIP_MEMORY_SCOPE_AGENT);
              u64 q1 = __hip_atomic_load(wp + 1, __ATOMIC_RELAXED, __HIP_MEMORY_SCOPE_AGENT);
              u64 q2 = __hip_atomic_load(wp + 2, __ATOMIC_RELAXED, __HIP_MEMORY_SCOPE_AGENT);
              ok &= (int)(((unsigned)(q0 >> 48) == tg) & ((unsigned)(q1 >> 48) == tg) &
                          ((unsigned)(q2 >> 48) == tg));
              union { unsigned u[4]; short8 v; } fu;
              unsigned b0 = (unsigned)q1;
              fu.u[0] = (unsigned)q0;
              fu.u[1] = ((unsigned)(q0 >> 32) & 0xffffu) | (b0 << 16);
              fu.u[2] = (b0 >> 16) | ((unsigned)(q1 >> 32) << 16);
              fu.u[3] = (unsigned)q2;
              af[mi * 4 + ks] = fu.v;
            }
          }
          if (__all(ok)) break;
          __builtin_amdgcn_s_sleep(2);
        }
      }
    }
#pragma unroll
    for (int i = 0; i < 8; ++i) asm volatile("" : "+v"(af[i]));

    // --- C) partial gates: 2 m-tiles x 4 gates ---
    f32x4 acc[2][4] = {};
#pragma unroll
    for (int ks = 0; ks < 4; ++ks) {
#pragma unroll
      for (int mi = 0; mi < 2; ++mi)
#pragma unroll
        for (int ni = 0; ni < 4; ++ni)
          acc[mi][ni] = __builtin_amdgcn_mfma_f32_16x16x32_bf16(
              af[mi * 4 + ks], wfr[ni * 4 + ks], acc[mi][ni], 0, 0, 0);
    }
    // --- D) partials, r8 layout [kq][gate-slot][batch] stride 35 ---
#pragma unroll
    for (int mi = 0; mi < 2; ++mi)
#pragma unroll
      for (int ni = 0; ni < 4; ++ni)
#pragma unroll
        for (int r = 0; r < 4; ++r)
          part[(kq * 64 + ni * 16 + (lane & 15)) * 35 + mi * 16 + (lane >> 4) * 4 + r] = acc[mi][ni][r];
    __syncthreads();

    // --- E) update: scalar reduce (conflict-free), activate, publish, y ---
    if (tid < 128) {
      const int c7 = cg * 4;
      float hv[4];
      union { u64 u; short s[4]; } pk;
#pragma unroll
      for (int j = 0; j < 4; ++j) {
        float gi = bf2f(pgi[j]), gf = bf2f(pgf[j]), gg = bf2f(pgg[j]), go = bf2f(pgo[j]);
#pragma unroll
        for (int q = 0; q < 8; ++q) {
          gi += part[(q * 64      + c7 + j) * 35 + b4];
          gf += part[(q * 64 + 16 + c7 + j) * 35 + b4];
          gg += part[(q * 64 + 32 + c7 + j) * 35 + b4];
          go += part[(q * 64 + 48 + c7 + j) * 35 + b4];
        }
        float i_ = fminf(fmaxf(0.2f * gi + 0.5f, 0.f), 1.f);
        float f_ = fminf(fmaxf(0.2f * gf + 0.5f, 0.f), 1.f);
        float g_ = fminf(fmaxf(gg, -1.f), 1.f);
        float o_ = fminf(fmaxf(0.2f * go + 0.5f, 0.f), 1.f);
        float cc = f_ * ca[j] + i_ * g_;
        ca[j] = cc;
        hv[j] = o_ * fminf(fmaxf(cc, -1.f), 1.f);
        pk.s[j] = f2bf(hv[j]);
      }
      if (ts < 511) {
        const unsigned tp = (unsigned)(lbase | (ts + 2));
        const u64 tagw = (u64)tp << 48;
        unsigned oddlo = (unsigned)__shfl_xor((int)(unsigned)pk.u, 1);
        u64* wb = hbuf + (size_t)(((ts + 2) & 15) * 2 + dir) * 12288 + ((size_t)b4 * 128 + g_own) * 3;
        if ((cg & 1) == 0) {
          __hip_atomic_store(wb,     (pk.u & 0x0000ffffffffffffull) | tagw,
                             __ATOMIC_RELAXED, __HIP_MEMORY_SCOPE_AGENT);
          __hip_atomic_store(wb + 1, (pk.u >> 48) | ((u64)oddlo << 16) | tagw,
                             __ATOMIC_RELAXED, __HIP_MEMORY_SCOPE_AGENT);
        } else {
          __hip_atomic_store(wb + 2, ((pk.u >> 32) & 0xffffffffull) | tagw,
                             __ATOMIC_RELAXED, __HIP_MEMORY_SCOPE_AGENT);
        }
        asm volatile("s_waitcnt vmcnt(0)" ::: "memory");         // ack h (y not in flight)
        if ((tid & 63) == 0)
          __hip_atomic_store(seq + (wid * 2 + (tid >> 6)) * 32, (int)tp,
                             __ATOMIC_RELAXED, __HIP_MEMORY_SCOPE_AGENT);
      }
      // y-store + next gx prefetch: off the critical path
      size_t yi = ((size_t)(t * 32 + b4)) * 2048 + dir * 1024 + col0;
      if (LAST) {
        float4 f4; f4.x = hv[0]; f4.y = hv[1]; f4.z = hv[2]; f4.w = hv[3];
        *(float4*)((float*)yout + yi) = f4;
      } else {
        short4v ys; ys.x = pk.s[0]; ys.y = pk.s[1]; ys.z = pk.s[2]; ys.w = pk.s[3];
        *(short4v*)((short*)yout + yi) = ys;
      }
      if (ts < 511) {
        const int tn = dir ? (511 - (ts + 1)) : (ts + 1);
        const short* gp = gx + ((size_t)(tn * 32 + b4)) * 8192 + dir * 4096 + col0;
        pgi = *(const short4v*)(gp);
        pgf = *(const short4v*)(gp + 1024);
        pgg = *(const short4v*)(gp + 2048);
        pgo = *(const short4v*)(gp + 3072);
      }
    }
    __syncthreads();                        // release part for next step's writes
  }
}

// ---------------- host ----------------
extern "C" void kernel_launch(void* const* d_in, const int* in_sizes, int n_in,
                              void* d_out, int out_size, void* d_ws, size_t ws_size,
                              hipStream_t stream)
{
  const float* x  = (const float*)d_in[0];
  const float* h0 = (const float*)d_in[1];
  const float* c0 = (const float*)d_in[2];
  auto W = [&](int l, int d, int k) { return (const float*)d_in[3 + l * 8 + d * 4 + k]; };
  // k: 0=w_ih, 1=w_hh, 2=b_ih, 3=b_hh

  char* base = (char*)d_ws;
  size_t off = 0;
  auto alloc = [&](size_t bytes) {
    void* p = base + off;
    off = (off + bytes + 255) & ~(size_t)255;
    return p;
  };
  // ws budget ~512 MiB: keep total well under (r11 overflow lesson).
  short* xb    = (short*)alloc(16384ull * 320 * 2);
  short* wih0  = (short*)alloc(8192ull * 320 * 2);
  short* wih1  = (short*)alloc(8192ull * 2048 * 2);
  short* wih2  = (short*)alloc(8192ull * 2048 * 2);
  short* whh0  = (short*)alloc(8192ull * 1024 * 2);
  short* whh1  = (short*)alloc(8192ull * 1024 * 2);
  short* whh2  = (short*)alloc(8192ull * 1024 * 2);
  float* bias0 = (float*)alloc(8192ull * 4);
  float* bias1 = (float*)alloc(8192ull * 4);
  float* bias2 = (float*)alloc(8192ull * 4);
  short* gx    = (short*)alloc(16384ull * 8192 * 2);
  short* ybuf  = (short*)alloc(16384ull * 2048 * 2);  // scan0 out AND scan1 out:
  // y(l) is dead once gemm(l+1) has read it (stream-ordered), so both
  // intermediate layer outputs share this one buffer.
  // hbuf: 16 slots x 2 dir x 12288 tagged u64 (3 MB) + seq hints (32 KB)
  u64*   hbuf  = (u64*)alloc(393216ull * 8 + 2ull * 4096 * 4);
  (void)ws_size; (void)in_sizes; (void)n_in; (void)out_size;

  auto cvt = [&](const float* s, short* d, size_t n) {
    size_t want = (n / 4 + 255) / 256;
    int blocks = (int)(want > 2048 ? 2048 : want);
    k_cvt<<<dim3(blocks), dim3(256), 0, stream>>>(s, d, (int)n);
  };

  cvt(x, xb, 16384ull * 320);
  short* wihs[3] = { wih0, wih1, wih2 };
  short* whhs[3] = { whh0, whh1, whh2 };
  float* biases[3] = { bias0, bias1, bias2 };
  for (int l = 0; l < 3; ++l) {
    size_t kin = (l == 0) ? 320 : 2048;
    cvt(W(l, 0, 0), wihs[l],                  4096 * kin);
    cvt(W(l, 1, 0), wihs[l] + 4096 * kin,     4096 * kin);
    cvt(W(l, 0, 1), whhs[l],                  4096ull * 1024);
    cvt(W(l, 1, 1), whhs[l] + 4096ull * 1024, 4096ull * 1024);
    k_bias<<<dim3(32), dim3(256), 0, stream>>>(W(l, 0, 2), W(l, 0, 3), W(l, 1, 2), W(l, 1, 3), biases[l]);
  }

  const int M = 16384, N = 8192;
  const int LDSB = 8 * 64 * 35 * 4;         // 71680 B dynamic LDS

  // ---- layer 0 ----
  k_gemm<<<dim3((M / 128) * (N / 128)), dim3(256), 0, stream>>>(xb, wih0, bias0, gx, M, N, 320);
  k_scan<false><<<dim3(128), dim3(512), LDSB, stream>>>(gx, whh0, h0, c0, hbuf, (void*)ybuf, 0);
  // ---- layer 1 ----
  k_gemm<<<dim3((M / 128) * (N / 128)), dim3(256), 0, stream>>>(ybuf, wih1, bias1, gx, M, N, 2048);
  k_scan<false><<<dim3(128), dim3(512), LDSB, stream>>>(gx, whh1, h0, c0, hbuf, (void*)ybuf, 1);
  // ---- layer 2 ----
  k_gemm<<<dim3((M / 128) * (N / 128)), dim3(256), 0, stream>>>(ybuf, wih2, bias2, gx, M, N, 2048);
  k_scan<true><<<dim3(128), dim3(512), LDSB, stream>>>(gx, whh2, h0, c0, hbuf, d_out, 2);
}